// Round 12
// baseline (29.810 us; speedup 1.0000x reference)
//
#include <hip/hip_runtime.h>
#include <math.h>

#define LQ 256
#define MEML 256
#define LK 512
#define BB 4
#define NH 8
#define DM 128

#define IT 8                  // i-tile per score block (20 KB LDS -> 8 blocks/CU)
#define QSTRIDE 20            // LDS q row stride (floats): 80B, 16B-aligned

constexpr float INV2PI = 0.15915494309189535f;

// ---------------------------------------------------------------------------
// Projection (identical to R11), pre-scaled by paramR[h]/(2*pi):
//   qs[(i*4+b)*128 + h*16+d]   ( == (i*32+b*8+h)*16 + d )
//   ksT[((d>>2)*512 + j)*128 + (b*8+h)*4 + (d&3)]
// ---------------------------------------------------------------------------
__global__ __launch_bounds__(128) void proj_kernel(
    const float* __restrict__ hh, const float* __restrict__ mems,
    const float* __restrict__ Wq, const float* __restrict__ Wk,
    const float* __restrict__ paramR,
    float* __restrict__ qs, float* __restrict__ ksT)
{
    __shared__ float x[8 * 128];
    const int blk = blockIdx.x;
    const int t = threadIdx.x;
    const bool isQ = (blk < 128);                 // 128 q-blocks, 256 k-blocks
    const int row0 = isQ ? blk * 8 : (blk - 128) * 8;
    const float* __restrict__ W = isQ ? Wq : Wk;

    for (int r = 0; r < 8; ++r) {
        const int row = row0 + r;
        const float* src = isQ ? (hh + row * DM)
                               : ((row < MEML * BB) ? (mems + row * DM)
                                                    : (hh + (row - MEML * BB) * DM));
        x[r * 128 + t] = src[t];
    }
    __syncthreads();

    float acc[8] = {0, 0, 0, 0, 0, 0, 0, 0};
    const float* wrow = W + t * DM;
    for (int k = 0; k < DM; k += 4) {
        const float4 w = *(const float4*)(wrow + k);
        #pragma unroll
        for (int r = 0; r < 8; ++r) {
            acc[r] += x[r * 128 + k + 0] * w.x + x[r * 128 + k + 1] * w.y
                    + x[r * 128 + k + 2] * w.z + x[r * 128 + k + 3] * w.w;
        }
    }
    const int h = t >> 4, d = t & 15;
    const float rs = paramR[h] * INV2PI;
    if (isQ) {
        float* dst = qs + row0 * 128 + t;
        #pragma unroll
        for (int r = 0; r < 8; ++r) dst[r * 128] = acc[r] * rs;
    } else {
        #pragma unroll
        for (int r = 0; r < 8; ++r) {
            const int row = row0 + r;
            const int j = row >> 2, b = row & 3;
            ksT[((d >> 2) * LK + j) * 128 + (b * 8 + h) * 4 + (d & 3)] = acc[r] * rs;
        }
    }
}

// ---------------------------------------------------------------------------
// Score (R11 + conflict-free LDS reads). Lanes {bh,bh+8,bh+16,bh+24} share a
// bank-base (stride 20 * 8 = 160 = 0 mod 32); at read step s each lane reads
// PHYSICAL chunk (s ^ (bh>>3)) -> 4 distinct bank groups -> conflict-free.
// k is loaded with the SAME chunk permutation (runtime address, compile-time
// register index) so q[s]/k[s] always hold the same logical d's.
// ---------------------------------------------------------------------------
__global__ __launch_bounds__(256, 8) void score_kernel(
    const float* __restrict__ qs, const float* __restrict__ ksT,
    float* __restrict__ out)
{
    __shared__ float qt[IT * 32 * QSTRIDE];       // 20480 B exactly
    const int t = threadIdx.x;
    const int bh = t & 31;
    const int js = t >> 5;                        // 0..7
    const int key = bh >> 3;                      // 0..3 chunk-permutation key
    const int i0 = blockIdx.x * IT;               // 32 i-tiles
    const int j = blockIdx.y * 8 + js;            // 64 j-tiles of 8

    constexpr float i2 = INV2PI * INV2PI;
    constexpr float i4 = i2 * i2;
    constexpr float i8 = i4 * i4;
    constexpr float C16 = i8 * i8;                // (2pi)^-16
    constexpr float EPS = 2.0e-4f * INV2PI;       // 3.18e-5 rev; EPS^8 > FLT_MIN

    // stage q-tile: IT*32*16 = 4096 contiguous floats -> padded LDS rows
    // (writes keep natural chunk slots; only 2-way aliasing = free)
    {
        const float* src = qs + i0 * 32 * 16;
        #pragma unroll
        for (int rep = 0; rep < 4; ++rep) {
            const int c4 = rep * 256 + t;         // float4 chunk id, 0..1023
            const int row = c4 >> 2, cc = (c4 & 3) * 4;
            const float4 v = *(const float4*)(src + c4 * 4);
            *(float4*)(&qt[row * QSTRIDE + cc]) = v;
        }
    }

    // k resident in 16 VGPRs, chunk-permuted to match the swizzled q reads
    float k[16];
    #pragma unroll
    for (int s = 0; s < 4; ++s) {
        const int plane = s ^ key;                // runtime address, fine
        const float4 v = *(const float4*)(ksT + (plane * LK + j) * 128 + bh * 4);
        k[s * 4 + 0] = v.x; k[s * 4 + 1] = v.y;
        k[s * 4 + 2] = v.z; k[s * 4 + 3] = v.w;
    }
    __syncthreads();

    #pragma unroll 4
    for (int ii = 0; ii < IT; ++ii) {
        const float* qrow = &qt[(ii * 32 + bh) * QSTRIDE];
        float q[16];
        #pragma unroll
        for (int s = 0; s < 4; ++s) {
            const float4 v = *(const float4*)(qrow + ((s ^ key) << 2));
            q[s * 4 + 0] = v.x; q[s * 4 + 1] = v.y;
            q[s * 4 + 2] = v.z; q[s * 4 + 3] = v.w;
        }
        float pn0 = 1.f, pd0 = 1.f, pn1 = 1.f, pd1 = 1.f;
        #pragma unroll
        for (int d = 0; d < 16; ++d) {
            const float u2 = fmaxf(__builtin_fabsf(q[d] - k[d]), EPS);
            const float s = __builtin_amdgcn_sinf(u2);   // sin(2pi*u2)
            if (d < 8) { pn0 *= s; pd0 *= u2; }
            else       { pn1 *= s; pd1 *= u2; }
        }
        const float r0 = pn0 * __builtin_amdgcn_rcpf(pd0);
        const float r1 = pn1 * __builtin_amdgcn_rcpf(pd1);
        out[((i0 + ii) * LK + j) * 32 + bh] = __builtin_fabsf(r0 * r1) * C16;
    }
}

extern "C" void kernel_launch(void* const* d_in, const int* in_sizes, int n_in,
                              void* d_out, int out_size, void* d_ws, size_t ws_size,
                              hipStream_t stream) {
    const float* hh     = (const float*)d_in[0];
    const float* mems   = (const float*)d_in[1];
    const float* Wq     = (const float*)d_in[2];
    const float* Wk     = (const float*)d_in[3];
    const float* paramR = (const float*)d_in[4];
    float* out = (float*)d_out;

    float* qs  = (float*)d_ws;                // 131072 floats
    float* ksT = qs + LQ * BB * DM;           // 262144 floats

    proj_kernel<<<384, 128, 0, stream>>>(hh, mems, Wq, Wk, paramR, qs, ksT);
    score_kernel<<<dim3(LQ / IT, LK / 8), 256, 0, stream>>>(qs, ksT, out);
}

// Round 13
// 29.751 us; speedup vs baseline: 1.0020x; 1.0020x over previous
//
#include <hip/hip_runtime.h>
#include <math.h>

#define LQ 256
#define MEML 256
#define LK 512
#define BB 4
#define NH 8
#define DM 128

#define IT 8                  // i-tile per score block (20 KB LDS)
#define QSTRIDE 20            // LDS q row stride (floats): 80B, 16B-aligned

constexpr float INV2PI = 0.15915494309189535f;

// ---------------------------------------------------------------------------
// Projection (identical to R11/R12), pre-scaled by paramR[h]/(2*pi):
//   qs[(i*4+b)*128 + h*16+d]   ( == (i*32+b*8+h)*16 + d )
//   ksT[((d>>2)*512 + j)*128 + (b*8+h)*4 + (d&3)]
// ---------------------------------------------------------------------------
__global__ __launch_bounds__(128) void proj_kernel(
    const float* __restrict__ hh, const float* __restrict__ mems,
    const float* __restrict__ Wq, const float* __restrict__ Wk,
    const float* __restrict__ paramR,
    float* __restrict__ qs, float* __restrict__ ksT)
{
    __shared__ float x[8 * 128];
    const int blk = blockIdx.x;
    const int t = threadIdx.x;
    const bool isQ = (blk < 128);                 // 128 q-blocks, 256 k-blocks
    const int row0 = isQ ? blk * 8 : (blk - 128) * 8;
    const float* __restrict__ W = isQ ? Wq : Wk;

    for (int r = 0; r < 8; ++r) {
        const int row = row0 + r;
        const float* src = isQ ? (hh + row * DM)
                               : ((row < MEML * BB) ? (mems + row * DM)
                                                    : (hh + (row - MEML * BB) * DM));
        x[r * 128 + t] = src[t];
    }
    __syncthreads();

    float acc[8] = {0, 0, 0, 0, 0, 0, 0, 0};
    const float* wrow = W + t * DM;
    for (int k = 0; k < DM; k += 4) {
        const float4 w = *(const float4*)(wrow + k);
        #pragma unroll
        for (int r = 0; r < 8; ++r) {
            acc[r] += x[r * 128 + k + 0] * w.x + x[r * 128 + k + 1] * w.y
                    + x[r * 128 + k + 2] * w.z + x[r * 128 + k + 3] * w.w;
        }
    }
    const int h = t >> 4, d = t & 15;
    const float rs = paramR[h] * INV2PI;
    if (isQ) {
        float* dst = qs + row0 * 128 + t;
        #pragma unroll
        for (int r = 0; r < 8; ++r) dst[r * 128] = acc[r] * rs;
    } else {
        #pragma unroll
        for (int r = 0; r < 8; ++r) {
            const int row = row0 + r;
            const int j = row >> 2, b = row & 3;
            ksT[((d >> 2) * LK + j) * 128 + (b * 8 + h) * 4 + (d & 3)] = acc[r] * rs;
        }
    }
}

// ---------------------------------------------------------------------------
// Score, ILP/amortization restructure: 512 threads = (jj = t>>5: 16 j's,
// bh = t&31). IT=8 i's staged in LDS once (20 KB, swizzled reads); k[16] in
// VGPRs once. 1024 blocks (half the prologues of R12). launch_bounds(512,2)
// lifts the 64-VGPR cap so unroll-4 over ii REALLY materializes 4 independent
// q-states and 16 interleaved multiply chains per thread (ILP replaces TLP).
// ---------------------------------------------------------------------------
__global__ __launch_bounds__(512, 2) void score_kernel(
    const float* __restrict__ qs, const float* __restrict__ ksT,
    float* __restrict__ out)
{
    __shared__ float qt[IT * 32 * QSTRIDE];       // 20480 B
    const int t = threadIdx.x;
    const int bh = t & 31;
    const int jj = t >> 5;                        // 0..15
    const int key = bh >> 3;                      // 0..3 chunk-permutation key
    const int i0 = blockIdx.x * IT;               // 32 i-tiles
    const int j = blockIdx.y * 16 + jj;           // 32 j-tiles of 16

    constexpr float i2 = INV2PI * INV2PI;
    constexpr float i4 = i2 * i2;
    constexpr float i8 = i4 * i4;
    constexpr float C16 = i8 * i8;                // (2pi)^-16
    constexpr float EPS = 2.0e-4f * INV2PI;       // 3.18e-5 rev; EPS^8 > FLT_MIN

    // stage q-tile: IT*32*16 = 4096 contiguous floats -> padded LDS rows
    {
        const float* src = qs + i0 * 32 * 16;
        #pragma unroll
        for (int rep = 0; rep < 2; ++rep) {
            const int c4 = rep * 512 + t;         // float4 chunk id, 0..1023
            const int row = c4 >> 2, cc = (c4 & 3) * 4;
            const float4 v = *(const float4*)(src + c4 * 4);
            *(float4*)(&qt[row * QSTRIDE + cc]) = v;
        }
    }

    // k resident in 16 VGPRs, chunk-permuted to match the swizzled q reads
    float k[16];
    #pragma unroll
    for (int s = 0; s < 4; ++s) {
        const int plane = s ^ key;
        const float4 v = *(const float4*)(ksT + (plane * LK + j) * 128 + bh * 4);
        k[s * 4 + 0] = v.x; k[s * 4 + 1] = v.y;
        k[s * 4 + 2] = v.z; k[s * 4 + 3] = v.w;
    }
    __syncthreads();

    #pragma unroll 4
    for (int ii = 0; ii < IT; ++ii) {
        const float* qrow = &qt[(ii * 32 + bh) * QSTRIDE];
        float q[16];
        #pragma unroll
        for (int s = 0; s < 4; ++s) {
            const float4 v = *(const float4*)(qrow + ((s ^ key) << 2));
            q[s * 4 + 0] = v.x; q[s * 4 + 1] = v.y;
            q[s * 4 + 2] = v.z; q[s * 4 + 3] = v.w;
        }
        float pn0 = 1.f, pd0 = 1.f, pn1 = 1.f, pd1 = 1.f;
        #pragma unroll
        for (int d = 0; d < 16; ++d) {
            const float u2 = fmaxf(__builtin_fabsf(q[d] - k[d]), EPS);
            const float s = __builtin_amdgcn_sinf(u2);   // sin(2pi*u2)
            if (d < 8) { pn0 *= s; pd0 *= u2; }
            else       { pn1 *= s; pd1 *= u2; }
        }
        const float r0 = pn0 * __builtin_amdgcn_rcpf(pd0);
        const float r1 = pn1 * __builtin_amdgcn_rcpf(pd1);
        out[((i0 + ii) * LK + j) * 32 + bh] = __builtin_fabsf(r0 * r1) * C16;
    }
}

extern "C" void kernel_launch(void* const* d_in, const int* in_sizes, int n_in,
                              void* d_out, int out_size, void* d_ws, size_t ws_size,
                              hipStream_t stream) {
    const float* hh     = (const float*)d_in[0];
    const float* mems   = (const float*)d_in[1];
    const float* Wq     = (const float*)d_in[2];
    const float* Wk     = (const float*)d_in[3];
    const float* paramR = (const float*)d_in[4];
    float* out = (float*)d_out;

    float* qs  = (float*)d_ws;                // 131072 floats
    float* ksT = qs + LQ * BB * DM;           // 262144 floats

    proj_kernel<<<384, 128, 0, stream>>>(hh, mems, Wq, Wk, paramR, qs, ksT);
    score_kernel<<<dim3(LQ / IT, LK / 16), 512, 0, stream>>>(qs, ksT, out);
}